// Round 8
// baseline (180.888 us; speedup 1.0000x reference)
//
#include <hip/hip_runtime.h>
#include <stdint.h>

#define B_ 4
#define C_ 256
#define C8_ 32
#define N_ 4096
#define LOG2E 1.4426950408889634f
#define INV_SQRT32 0.17677669529663689f
#define QSCALE (INV_SQRT32 * LOG2E)

typedef __bf16 bf16x8 __attribute__((ext_vector_type(8)));
typedef float f32x16 __attribute__((ext_vector_type(16)));
typedef unsigned int uint4v __attribute__((ext_vector_type(4)));

__device__ __forceinline__ uint16_t f2bf(float f) {
  uint32_t u = __builtin_bit_cast(uint32_t, f);
  return (uint16_t)((u + 0x7FFFu + ((u >> 16) & 1u)) >> 16);
}
__device__ __forceinline__ uint32_t pack2bf(float a, float b) {
  uint32_t ua = __builtin_bit_cast(uint32_t, a);
  uint32_t ub = __builtin_bit_cast(uint32_t, b);
  ua = (ua + 0x7FFFu + ((ua >> 16) & 1u)) >> 16;
  ub = (ub + 0x7FFFu + ((ub >> 16) & 1u)) & 0xFFFF0000u;
  return ua | ub;
}
__device__ __forceinline__ bf16x8 load_bf8(const uint16_t* p) {
  uint4v u = *(const uint4v*)p;
  return __builtin_bit_cast(bf16x8, u);
}
__device__ __forceinline__ f32x16 mfma32(bf16x8 a, bf16x8 b, f32x16 c) {
  return __builtin_amdgcn_mfma_f32_32x32x16_bf16(a, b, c, 0, 0, 0);
}
__device__ __forceinline__ f32x16 mfma32_f8(long a, long b, f32x16 c) {
  return __builtin_amdgcn_mfma_f32_32x32x16_fp8_fp8(a, b, c, 0, 0, 0);
}

// P rows (C/D layout) -> fp8 A-operand pair via xor32 exchange
__device__ __forceinline__ void pack_p_fp8(const float* P, int h, long& pa, long& pb) {
  uint32_t w0 = __builtin_amdgcn_cvt_pk_fp8_f32(P[0], P[1], 0, false);
  w0 = __builtin_amdgcn_cvt_pk_fp8_f32(P[2], P[3], w0, true);
  uint32_t w1 = __builtin_amdgcn_cvt_pk_fp8_f32(P[4], P[5], 0, false);
  w1 = __builtin_amdgcn_cvt_pk_fp8_f32(P[6], P[7], w1, true);
  uint32_t w2 = __builtin_amdgcn_cvt_pk_fp8_f32(P[8], P[9], 0, false);
  w2 = __builtin_amdgcn_cvt_pk_fp8_f32(P[10], P[11], w2, true);
  uint32_t w3 = __builtin_amdgcn_cvt_pk_fp8_f32(P[12], P[13], 0, false);
  w3 = __builtin_amdgcn_cvt_pk_fp8_f32(P[14], P[15], w3, true);
  uint32_t s0 = h ? w0 : w1;
  uint32_t s1 = h ? w2 : w3;
  uint32_t r0 = (uint32_t)__shfl_xor((int)s0, 32, 64);
  uint32_t r1 = (uint32_t)__shfl_xor((int)s1, 32, 64);
  uint32_t a0lo = h ? r0 : w0, a0hi = h ? w1 : r0;
  uint32_t a1lo = h ? r1 : w2, a1hi = h ? w3 : r1;
  pa = (long)(((uint64_t)a0hi << 32) | a0lo);
  pb = (long)(((uint64_t)a1hi << 32) | a1lo);
}

// ---------------- kernel 0: weight cast to k-group-packed bf16 -------------
__global__ void k_wcast(const float* __restrict__ wq, const float* __restrict__ wk,
                        const float* __restrict__ wv, const float* __restrict__ wo,
                        uint16_t* __restrict__ wqb, uint16_t* __restrict__ wkb,
                        uint16_t* __restrict__ wvb, uint16_t* __restrict__ wob) {
  int i = blockIdx.x * 256 + threadIdx.x;  // total 147456
  if (i < 8192) {
    int o = i >> 8, c = i & 255;
    wqb[((size_t)(c >> 3) * 32 + o) * 8 + (c & 7)] = f2bf(wq[i]);
  } else if (i < 16384) {
    int j = i - 8192; int o = j >> 8, c = j & 255;
    wkb[((size_t)(c >> 3) * 32 + o) * 8 + (c & 7)] = f2bf(wk[j]);
  } else if (i < 81920) {
    int j = i - 16384; int o = j >> 8, c = j & 255;
    wvb[((size_t)(c >> 3) * 256 + o) * 8 + (c & 7)] = f2bf(wv[j]);
  } else {
    int j = i - 81920; int o = j >> 8, c = j & 255;
    wob[((size_t)(c >> 3) * 256 + o) * 8 + (c & 7)] = f2bf(wo[j]);
  }
}

// ---------------- kernel 1: fused transpose + QKV projection ---------------
// Block = 32 spatial cols. Stage x[256c][32n] f32 -> bf16 frags in LDS via
// wide b128 writes, then 5 waves: wave0 = q+k, waves1-4 = V (fp8).
__global__ __launch_bounds__(320) void k_proj_qkv(
    const float* __restrict__ x,
    const uint16_t* __restrict__ wqb, const float* __restrict__ bq,
    const uint16_t* __restrict__ wkb, const float* __restrict__ bk,
    const uint16_t* __restrict__ wvb, const float* __restrict__ bv,
    uint16_t* __restrict__ Qb, uint16_t* __restrict__ Kt, uint8_t* __restrict__ V8) {
  __shared__ uint4v xTv[32 * 32];  // [cg][n] fragments, 16 KB
  int b = blockIdx.y;
  int n0 = blockIdx.x * 32;
  int tid = threadIdx.x;

  if (tid < 256) {
    int n = tid & 31;
    int cg0 = tid >> 5;          // 0..7
#pragma unroll
    for (int j = 0; j < 4; j++) {
      int cg = cg0 * 4 + j;
      const float* xp = x + ((size_t)b * C_ + cg * 8) * N_ + n0 + n;
      float v[8];
#pragma unroll
      for (int c = 0; c < 8; c++) v[c] = xp[(size_t)c * N_];
      uint4v o;
#pragma unroll
      for (int p = 0; p < 4; p++) o[p] = pack2bf(v[2 * p], v[2 * p + 1]);
      xTv[cg * 32 + n] = o;      // single ds_write_b128, 16B lane stride
    }
  }
  __syncthreads();

  int wave = tid >> 6;
  int lane = tid & 63;
  int h = lane >> 5, ln = lane & 31;

  if (wave == 0) {
    f32x16 aq, ak;
#pragma unroll
    for (int i = 0; i < 16; i++) { aq[i] = 0.0f; ak[i] = 0.0f; }
#pragma unroll 4
    for (int c = 0; c < C_; c += 16) {
      bf16x8 bb = __builtin_bit_cast(bf16x8, xTv[(c / 8 + h) * 32 + ln]);
      aq = mfma32(load_bf8(wqb + ((size_t)(c / 8 + h) * 32 + ln) * 8), bb, aq);
      ak = mfma32(load_bf8(wkb + ((size_t)(c / 8 + h) * 32 + ln) * 8), bb, ak);
    }
#pragma unroll
    for (int g = 0; g < 4; g++) {
      int row = g * 8 + h * 4;
      uint2 pq, pk;
      pq.x = pack2bf((aq[4 * g + 0] + bq[row + 0]) * QSCALE,
                     (aq[4 * g + 1] + bq[row + 1]) * QSCALE);
      pq.y = pack2bf((aq[4 * g + 2] + bq[row + 2]) * QSCALE,
                     (aq[4 * g + 3] + bq[row + 3]) * QSCALE);
      *(uint2*)(Qb + ((size_t)b * N_ + n0 + ln) * C8_ + row) = pq;
      pk.x = pack2bf(ak[4 * g + 0] + bk[row + 0], ak[4 * g + 1] + bk[row + 1]);
      pk.y = pack2bf(ak[4 * g + 2] + bk[row + 2], ak[4 * g + 3] + bk[row + 3]);
      *(uint2*)(Kt + ((size_t)(b * 4 + g) * N_ + n0 + ln) * 8 + h * 4) = pk;
    }
  } else {
    int o0 = (wave - 1) * 64;
    f32x16 a0, a1;
#pragma unroll
    for (int i = 0; i < 16; i++) { a0[i] = 0.0f; a1[i] = 0.0f; }
#pragma unroll 4
    for (int c = 0; c < C_; c += 16) {
      bf16x8 bb = __builtin_bit_cast(bf16x8, xTv[(c / 8 + h) * 32 + ln]);
      a0 = mfma32(load_bf8(wvb + ((size_t)(c / 8 + h) * 256 + o0 + ln) * 8), bb, a0);
      a1 = mfma32(load_bf8(wvb + ((size_t)(c / 8 + h) * 256 + o0 + 32 + ln) * 8), bb, a1);
    }
    int kg = b * 512 + (n0 >> 3) + (ln >> 3);
    int j = ln & 7;
#pragma unroll
    for (int r = 0; r < 16; r++) {
      int row = (r & 3) + 8 * (r >> 2) + 4 * h;
      float v0 = a0[r] + bv[o0 + row];
      float v1 = a1[r] + bv[o0 + 32 + row];
      int p0 = __builtin_amdgcn_cvt_pk_fp8_f32(v0, v0, 0, false);
      int p1 = __builtin_amdgcn_cvt_pk_fp8_f32(v1, v1, 0, false);
      V8[((size_t)kg * 256 + o0 + row) * 8 + j] = (uint8_t)(p0 & 0xff);
      V8[((size_t)kg * 256 + o0 + 32 + row) * 8 + j] = (uint8_t)(p1 & 0xff);
    }
  }
}

// ---------------- kernel 2: flash attention + fused out-proj + residual ----
// 512 blocks (XCD-pinned), 8 waves = kw(4) x cw(2), 32 q/block.
// Phase-staggered key order per wave decorrelates pipe usage of co-resident
// waves (anti-convoy). V loads batched ahead of the exp/pack phase.
__global__ __launch_bounds__(512, 4) void k_attn(
    const uint16_t* __restrict__ Qb, const uint16_t* __restrict__ Kt,
    const uint8_t* __restrict__ V8, const uint16_t* __restrict__ Wob,
    const float* __restrict__ bo, const float* __restrict__ x,
    const float* __restrict__ scale, float* __restrict__ out) {
  __shared__ uint32_t sO[8][2][8][64];  // 32 KB partial staging
  __shared__ uint4v aTv[32 * 32];       // attended frags [cg][q], 16 KB
  __shared__ float sl[4][32];

  int bx = blockIdx.x;             // 0..7 -> XCD
  int b = bx >> 1;
  int qt = blockIdx.y + 64 * (bx & 1);  // 0..127
  int wave = threadIdx.x >> 6;
  int kw = wave >> 1, cw = wave & 1;
  int lane = threadIdx.x & 63;
  int h = lane >> 5, ln = lane & 31;
  int qi = qt * 32 + ln;

  const uint16_t* qrow = Qb + ((size_t)b * N_ + qi) * C8_;
  bf16x8 qf1 = load_bf8(qrow + h * 8);
  bf16x8 qf2 = load_bf8(qrow + 16 + h * 8);
  const uint16_t* k1base = Kt + ((size_t)(b * 4 + h) * N_) * 8;
  const uint16_t* k2base = Kt + ((size_t)(b * 4 + 2 + h) * N_) * 8;

  f32x16 O[4];
#pragma unroll
  for (int t = 0; t < 4; t++)
#pragma unroll
    for (int r = 0; r < 16; r++) O[t][r] = 0.0f;
  float lsum = 0.0f;
  const uint8_t* vbase = V8 + (size_t)(b * 512) * 2048 + cw * 1024 + ln * 8;

  int m_lo = kw * 1024;
  int phase = wave * 4 + (blockIdx.y & 1) * 2;   // anti-convoy stagger
  int m0f = m_lo + ((phase & 31) << 5);
  bf16x8 ka1 = load_bf8(k1base + (size_t)(m0f + ln) * 8);
  bf16x8 ka2 = load_bf8(k2base + (size_t)(m0f + ln) * 8);

  for (int it = 0; it < 32; it++) {
    int m0 = m_lo + (((it + phase) & 31) << 5);
    int mp = m_lo + (((it + 1 + phase) & 31) << 5);
    bf16x8 kn1 = load_bf8(k1base + (size_t)(mp + ln) * 8);
    bf16x8 kn2 = load_bf8(k2base + (size_t)(mp + ln) * 8);

    // batch all V loads for this chunk (independent of S)
    const uint8_t* vp = vbase + (size_t)((m0 >> 3) + h) * 2048;
    uint2 u1[4], u2[4];
#pragma unroll
    for (int t = 0; t < 4; t++) {
      u1[t] = *(const uint2*)(vp + t * 256);
      u2[t] = *(const uint2*)(vp + 4096 + t * 256);
    }

    f32x16 S;
#pragma unroll
    for (int i = 0; i < 16; i++) S[i] = 0.0f;
    S = mfma32(ka1, qf1, S);
    S = mfma32(ka2, qf2, S);

    float P[16];
#pragma unroll
    for (int r = 0; r < 16; r++) {
      P[r] = __builtin_amdgcn_exp2f(fminf(S[r], 7.5f));
    }
    if (cw == 0) {
#pragma unroll
      for (int r = 0; r < 16; r++) lsum += P[r];
    }
    long pa, pb;
    pack_p_fp8(P, h, pa, pb);

#pragma unroll
    for (int t = 0; t < 4; t++) {
      long va = (long)(((uint64_t)u1[t].y << 32) | u1[t].x);
      long vc = (long)(((uint64_t)u2[t].y << 32) | u2[t].x);
      O[t] = mfma32_f8(va, pa, O[t]);
      O[t] = mfma32_f8(vc, pb, O[t]);
    }
    ka1 = kn1; ka2 = kn2;
  }
  if (cw == 0) {
    lsum += __shfl_xor(lsum, 32, 64);
    if (h == 0) sl[kw][ln] = lsum;
  }

  // ---- combine partials -> attended (normalized, bf16) in LDS ----
#pragma unroll
  for (int rr = 0; rr < 2; rr++) {
    if (rr) __syncthreads();
#pragma unroll
    for (int t2 = 0; t2 < 2; t2++) {
      int t = rr * 2 + t2;
#pragma unroll
      for (int i = 0; i < 8; i++)
        sO[wave][t2][i][lane] = pack2bf(O[t][2 * i], O[t][2 * i + 1]);
    }
    __syncthreads();
    if (wave < 4) {
      int cw2 = wave >> 1, t2 = wave & 1;
      int gt = cw2 * 4 + rr * 2 + t2;   // global 32-ch tile
      float acc[16];
#pragma unroll
      for (int r = 0; r < 16; r++) acc[r] = 0.0f;
#pragma unroll
      for (int k = 0; k < 4; k++) {
        int src = k * 2 + cw2;
#pragma unroll
        for (int i = 0; i < 8; i++) {
          uint32_t u = sO[src][t2][i][lane];
          acc[2 * i]     += __builtin_bit_cast(float, u << 16);
          acc[2 * i + 1] += __builtin_bit_cast(float, u & 0xFFFF0000u);
        }
      }
      float lg = sl[0][ln] + sl[1][ln] + sl[2][ln] + sl[3][ln];
      float inv = 1.0f / lg;
      uint2* aT2 = (uint2*)aTv;
#pragma unroll
      for (int g = 0; g < 4; g++) {
        uint2 pr;
        pr.x = pack2bf(acc[4 * g + 0] * inv, acc[4 * g + 1] * inv);
        pr.y = pack2bf(acc[4 * g + 2] * inv, acc[4 * g + 3] * inv);
        aT2[((gt * 4 + g) * 32 + ln) * 2 + h] = pr;
      }
    }
  }
  __syncthreads();

  // ---- Wo GEMM + residual: wave w -> output channels [w*32, w*32+32) ----
  int o0 = wave * 32;
  f32x16 acc;
#pragma unroll
  for (int i = 0; i < 16; i++) acc[i] = 0.0f;
#pragma unroll 4
  for (int c = 0; c < C_; c += 16) {
    bf16x8 a = load_bf8(Wob + ((size_t)(c / 8 + h) * 256 + o0 + ln) * 8);
    bf16x8 bb = __builtin_bit_cast(bf16x8, aTv[(c / 8 + h) * 32 + ln]);
    acc = mfma32(a, bb, acc);
  }
  float s = scale[0];
#pragma unroll
  for (int r = 0; r < 16; r++) {
    int row = (r & 3) + 8 * (r >> 2) + 4 * h;
    int o = o0 + row;
    size_t idx = ((size_t)b * C_ + o) * N_ + qi;
    out[idx] = x[idx] + s * (acc[r] + bo[o]);
  }
}

extern "C" void kernel_launch(void* const* d_in, const int* in_sizes, int n_in,
                              void* d_out, int out_size, void* d_ws, size_t ws_size,
                              hipStream_t stream) {
  const float* x  = (const float*)d_in[0];
  const float* wq = (const float*)d_in[1];
  const float* bq = (const float*)d_in[2];
  const float* wk = (const float*)d_in[3];
  const float* bk = (const float*)d_in[4];
  const float* wv = (const float*)d_in[5];
  const float* bv = (const float*)d_in[6];
  const float* wo = (const float*)d_in[7];
  const float* bo = (const float*)d_in[8];
  const float* scale = (const float*)d_in[9];
  float* out = (float*)d_out;

  char* w = (char*)d_ws;
  uint16_t* Qb  = (uint16_t*)(w);                  // [B][N][32] bf16, 1 MB
  uint16_t* Kt  = (uint16_t*)(w + (1u << 20));     // [B][4][N][8] bf16, 1 MB
  uint8_t*  V8  = (uint8_t*)(w + (2u << 20));      // [B][512][256][8] fp8, 4 MB
  uint16_t* Wqb = (uint16_t*)(w + (6u << 20));     // weights bf16, ~294 KB
  uint16_t* Wkb = Wqb + 32 * 256;
  uint16_t* Wvb = Wkb + 32 * 256;
  uint16_t* Wob = Wvb + 256 * 256;

  k_wcast<<<576, 256, 0, stream>>>(wq, wk, wv, wo, Wqb, Wkb, Wvb, Wob);
  k_proj_qkv<<<dim3(N_ / 32, B_), 320, 0, stream>>>(x, Wqb, bq, Wkb, bk, Wvb, bv,
                                                    Qb, Kt, V8);
  k_attn<<<dim3(8, 64), 512, 0, stream>>>(Qb, Kt, V8, Wob, bo, x, scale, out);
}